// Round 8
// baseline (706.638 us; speedup 1.0000x reference)
//
#include <hip/hip_runtime.h>
#include <math.h>

#define NB 2
#define NQ 300
#define NC 80
#define MH 128
#define MW 128
#define OUT_H 512
#define OUT_W 512

// out layout (flat f32): scores [B*Q] | labels [B*Q] | boxes [B*Q*4] | masks [B*Q*512*512]
#define OFF_SCORES 0
#define OFF_LABELS (NB*NQ)
#define OFF_BOXES  (2*NB*NQ)
#define OFF_MASKS  (6*NB*NQ)   // 600+600+2400 = 3600

// bit-plane in d_ws: 1 u32 = 32 consecutive pixels of one output row.
// words per image = 512 rows * 16 words = 8192; total = 600*8192 = 4,915,200 (19.7MB)
#define WORDS_PER_ROW 16
#define WORDS_PER_IMG (OUT_H * WORDS_PER_ROW)

// phase-2 expander: fill-shaped. 3840 blocks * 256 thr * 40 iters * 4 px = 157,286,400
#define EXP_BLOCKS 3840
#define EXP_ITERS  40

typedef float f32x4 __attribute__((ext_vector_type(4)));

__device__ __forceinline__ float sigf(float x) {
    return 1.0f / (1.0f + expf(-x));
}

__global__ __launch_bounds__(256)
void sbl_kernel(const float* __restrict__ logits,
                const float* __restrict__ boxes,
                const float* __restrict__ presence,
                const int*   __restrict__ ts_boxes,
                float* __restrict__ out) {
    int i = blockIdx.x * blockDim.x + threadIdx.x;
    if (i >= NB * NQ) return;
    int b = i / NQ;

    const float* lg = logits + (size_t)i * NC;
    const float* pr = presence + (size_t)b * NC;
    float best = -1e30f;
    #pragma unroll 8
    for (int c = 0; c < NC; ++c) {
        float s = sigf(lg[c]) * sigf(pr[c]);
        best = fmaxf(best, s);
    }
    out[OFF_SCORES + i] = best;
    out[OFF_LABELS + i] = 1.0f;

    const float* bx = boxes + (size_t)i * 4;
    float cx = bx[0], cy = bx[1], w = bx[2], h = bx[3];
    float img_h = (float)ts_boxes[b * 2 + 0];
    float img_w = (float)ts_boxes[b * 2 + 1];
    float* ob = out + OFF_BOXES + (size_t)i * 4;
    ob[0] = (cx - 0.5f * w) * img_w;
    ob[1] = (cy - 0.5f * h) * img_h;
    ob[2] = (cx + 0.5f * w) * img_w;
    ob[3] = (cy + 0.5f * h) * img_h;
}

// Phase 1: bilinear 128->512 (half-pixel centers), sign-threshold, pack bits.
// Thread = (bq, y, w): computes 32 consecutive pixels of output row y
// (x = 32w .. 32w+31), which need input cols 8w-1 .. 8w+8 (clamped) from the
// two y-interp rows. Writes one u32 of sign bits; word index == thread index
// -> fully coalesced. Per 4 outputs within column-group t: weights
// (0.375,0.625),(0.125,0.875),(0.875,0.125),(0.625,0.375) on cols (t-1,t,t+1).
__global__ __launch_bounds__(256)
void mask_bits_kernel(const float* __restrict__ pm, unsigned int* __restrict__ bits_out) {
    int tid = blockIdx.x * 256 + threadIdx.x;     // [0, 600*512*16)
    int w  = tid & 15;
    int y  = (tid >> 4) & 511;
    int bq = tid >> 13;

    float sy = 0.25f * (float)y - 0.375f;
    int y0 = (int)floorf(sy);
    float fy = sy - (float)y0;                    // {0.125,0.375,0.625,0.875}
    int r0 = max(y0, 0);
    int r1 = min(y0 + 1, MH - 1);

    const float* base = pm + (size_t)bq * (MH * MW);
    const float* rowA = base + (size_t)r0 * MW;
    const float* rowB = base + (size_t)r1 * MW;

    float w1 = fy, w0 = 1.0f - fy;
    // y-interpolated input cols 8w-1 .. 8w+8 (10 values, clamped)
    float c[10];
    int cbase = 8 * w - 1;
    #pragma unroll
    for (int k = 0; k < 10; ++k) {
        int col = cbase + k;
        col = col < 0 ? 0 : (col > MW - 1 ? MW - 1 : col);
        c[k] = rowA[col] * w0 + rowB[col] * w1;
    }

    unsigned int bits = 0;
    #pragma unroll
    for (int g = 0; g < 8; ++g) {                 // column-group t = 8w+g
        float p = c[g], q = c[g + 1], r = c[g + 2];
        unsigned int b0 = (p * 0.375f + q * 0.625f) > 0.0f ? 1u : 0u;
        unsigned int b1 = (p * 0.125f + q * 0.875f) > 0.0f ? 1u : 0u;
        unsigned int b2 = (q * 0.875f + r * 0.125f) > 0.0f ? 1u : 0u;
        unsigned int b3 = (q * 0.625f + r * 0.375f) > 0.0f ? 1u : 0u;
        bits |= (b0 | (b1 << 1) | (b2 << 2) | (b3 << 3)) << (4 * g);
    }
    bits_out[tid] = bits;
}

// Phase 2: fill-shaped expander. Thread handles 4 pixels per iteration:
// one broadcast u32 load (8 lanes share a word, L1-served), nibble decode,
// one contiguous f32x4 store per lane (1KB/wave/instr). No dependency chain
// beyond the tiny load -> store issue stays dense like fillBufferAligned.
__global__ __launch_bounds__(256)
void mask_expand_kernel(const unsigned int* __restrict__ bits_in, float* __restrict__ out) {
    const int gstride = EXP_BLOCKS * 256;
    int gtid = blockIdx.x * 256 + threadIdx.x;
    float* mout = out + OFF_MASKS;

    #pragma unroll 4
    for (int it = 0; it < EXP_ITERS; ++it) {
        int idx = gtid + it * gstride;            // f32x4 index, [0, 39,321,600)
        unsigned int word = bits_in[idx >> 3];
        unsigned int n = (word >> ((idx & 7) * 4)) & 0xFu;
        f32x4 o;
        o.x = (n & 1u) ? 1.0f : 0.0f;
        o.y = (n & 2u) ? 1.0f : 0.0f;
        o.z = (n & 4u) ? 1.0f : 0.0f;
        o.w = (n & 8u) ? 1.0f : 0.0f;
        __builtin_nontemporal_store(o, (f32x4*)(mout + (size_t)idx * 4));
    }
}

extern "C" void kernel_launch(void* const* d_in, const int* in_sizes, int n_in,
                              void* d_out, int out_size, void* d_ws, size_t ws_size,
                              hipStream_t stream) {
    const float* pred_logits   = (const float*)d_in[0];
    const float* pred_boxes    = (const float*)d_in[1];
    const float* pred_masks    = (const float*)d_in[2];
    const float* presence      = (const float*)d_in[3];
    const int*   ts_boxes      = (const int*)d_in[4];
    (void)in_sizes; (void)n_in; (void)out_size; (void)ws_size;

    float* out = (float*)d_out;
    unsigned int* bits = (unsigned int*)d_ws;     // 19.7MB used

    sbl_kernel<<<(NB * NQ + 255) / 256, 256, 0, stream>>>(
        pred_logits, pred_boxes, presence, ts_boxes, out);

    // phase 1: 600*512*16 = 4,915,200 threads -> 19,200 blocks
    mask_bits_kernel<<<NB * NQ * OUT_H * WORDS_PER_ROW / 256, 256, 0, stream>>>(
        pred_masks, bits);

    // phase 2: pure expand/store stream
    mask_expand_kernel<<<EXP_BLOCKS, 256, 0, stream>>>(bits, out);
}